// Round 11
// baseline (1023.126 us; speedup 1.0000x reference)
//
#include <hip/hip_runtime.h>
#include <hip/hip_bf16.h>

// out = (1-z)*hidden + z*n
//   r = sig(in·(w_ir+w_hr)^T + b_ir+b_hr)
//   z = sig(in·(w_iz+w_hz)^T + b_iz+b_hz)
//   n = sig(in·w_in^T + b_in + r*(in·w_hn^T + b_hn))
// Fast path: prepass folds/converts weights+input to bf16 in d_ws in LDS-
// fragment order (1KB-contiguous global_load_lds), then a 4-deep-ring fused
// GEMM (BK=32, 4x32KB LDS buffers, stage 3 tiles ahead, counted vmcnt(4),
// reads for tile t+1 issued during tile t's MFMA -> LDS/MFMA pipes overlap).
// Fallback (ws too small): round-1 fp32-staged kernel (known passing).

#define THREADS 512
#define B_DIM 8192
#define D_DIM 4096
#define H_DIM 4096
#define BM 256
#define GBN 64              // per-gate output cols per block
#define BK 32
#define NT (D_DIM / BK)     // 128 K-tiles
#define TBYTES 32768        // LDS bytes per buffer: A 16KB + 4x4KB B

// ws layout (bytes)
#define WS_WR 0
#define WS_WZ 33554432
#define WS_WN 67108864
#define WS_WH 100663296
#define WS_A  134217728
#define WS_NEED 201326592ULL

typedef __attribute__((ext_vector_type(8))) short bf16x8;
typedef __attribute__((ext_vector_type(4))) float f32x4;
typedef __attribute__((ext_vector_type(4))) int i32x4;

__device__ __forceinline__ unsigned f2bf(float f) {
    union { float f; unsigned u; } v; v.f = f;
    return (v.u + 0x7FFFu + ((v.u >> 16) & 1u)) >> 16;   // RNE
}
__device__ __forceinline__ unsigned pk(float a, float b) {
    return (f2bf(a) & 0xFFFFu) | (f2bf(b) << 16);
}
__device__ __forceinline__ i32x4 pack8(float4 x, float4 y) {
    i32x4 r;
    r[0] = (int)pk(x.x, x.y); r[1] = (int)pk(x.z, x.w);
    r[2] = (int)pk(y.x, y.y); r[3] = (int)pk(y.z, y.w);
    return r;
}
__device__ __forceinline__ float sigmoidf_(float x) {
    return 1.0f / (1.0f + __expf(-x));
}
__device__ __forceinline__ void gld16(const void* g, void* l) {
    __builtin_amdgcn_global_load_lds(
        (const __attribute__((address_space(1))) unsigned*)g,
        (__attribute__((address_space(3))) unsigned*)l, 16, 0, 0);
}

// ---------------- prepass: fold/convert + permute into fragment order -----
// Frag = 16 rows x 32 k bf16 = 1KB; within-frag byte (C=kchunk 0..3)*256 +
// (R=row 0..15)*16  (== lane*16 for lane = C*16+R).
// A ws (64MB): [bblk 0..31][t 0..127][mfr 0..15][1KB]
// W ws (32MB/gate): [hblk 0..63][t 0..127][nfr 0..3][1KB]
__global__ __launch_bounds__(256) void prep_w_t(
    const float* __restrict__ ir, const float* __restrict__ hr,
    const float* __restrict__ iz, const float* __restrict__ hz,
    const float* __restrict__ inw, const float* __restrict__ hn,
    char* __restrict__ wsbase)
{
    const int tx = threadIdx.x;
    const int R = tx & 15;
    const int c8loc = tx >> 4;
    const int bx = blockIdx.x;
    const int c8blk = bx & 31;
    const int hgrp = bx >> 5;
    const int gy = blockIdx.y;
    const int h  = hgrp * 16 + R;
    const int c8 = c8blk * 16 + c8loc;     // k/8

    const float* s1 = (gy == 0) ? ir : (gy == 1) ? iz : (gy == 2) ? inw : hn;
    const size_t fi = ((size_t)h * 512 + c8) * 2;   // float4 index
    const float4* p1 = (const float4*)s1;
    float4 a0 = p1[fi], a1 = p1[fi + 1];
    if (gy < 2) {
        const float4* p2 = (const float4*)((gy == 0) ? hr : hz);
        a0 = a0 + p2[fi];
        a1 = a1 + p2[fi + 1];
    }
    const i32x4 v = pack8(a0, a1);
    const int hblk = h >> 6, nfr = (h >> 4) & 3;
    const int t = c8 >> 2, C = c8 & 3;
    const size_t addr = (size_t)gy * 33554432 + (size_t)hblk * 524288
                      + (size_t)t * 4096 + nfr * 1024 + C * 256 + R * 16;
    *(i32x4*)(wsbase + addr) = v;
}

__global__ __launch_bounds__(256) void prep_a_t(const float* __restrict__ in,
                                                char* __restrict__ abase)
{
    const int tx = threadIdx.x;
    const int R = tx & 15;
    const int c8loc = tx >> 4;
    const int bx = blockIdx.x;
    const int c8blk = bx & 31;
    const int bgrp = bx >> 5;
    const int b  = bgrp * 16 + R;
    const int c8 = c8blk * 16 + c8loc;

    const size_t fi = ((size_t)b * 512 + c8) * 2;
    const float4* p = (const float4*)in;
    const i32x4 v = pack8(p[fi], p[fi + 1]);
    const int bblk = b >> 8, mfr = (b >> 4) & 15;
    const int t = c8 >> 2, C = c8 & 3;
    const size_t addr = (size_t)bblk * 2097152 + (size_t)t * 16384
                      + mfr * 1024 + C * 256 + R * 16;
    *(i32x4*)(abase + addr) = v;
}

// ---------------- main bf16 kernel (4-deep ring, BK=32) -------------------
// LDS: 4 buffers x 32KB. Buffer q=t&3: A [0,16K) frag mfr*1024;
// Bg [16K+g*4K, +4K) frag nfr*1024. All lane-linear -> conflict-free.
//
// Pipeline (stage 3 ahead, publish 1 buffer per boundary barrier):
//   prologue: STAGE(0,1,2); vmcnt(4) [bufs 0,1 done]; barrier; RD(set0, 0)
//   BODY(t, cur, nxt):
//     lgkmcnt(0)              // reads(t) done (issued a full tile ago)
//     STAGE(t+3)              // 4 gld16 -> buf[(t+3)&3]
//     RD(nxt, t+1)            // 12 ds_read -> buf[(t+1)&3] (published at the
//                             //   barrier ending t-1: staged at t-2, drained
//                             //   by that boundary's vmcnt(4))
//     32 MFMA on cur          // ds_reads have no consumer until next tile ->
//                             //   scheduler spreads them through the MFMAs
//     vmcnt(4)|vmcnt(0); barrier   // drains stages issued at t-1 (buf t+2)
// WAR proof: STAGE(t+3) writes buf[(t-1)&3]; its last readers (reads(t-1))
// were lgkm-drained at BODY(t-1) head, before everyone's barrier ending t-1,
// and STAGE(t+3) is issued after that barrier.
__global__ __launch_bounds__(THREADS, 2) void gru_bf16(
    const char* __restrict__ Abf, const char* __restrict__ Wr,
    const char* __restrict__ Wz, const char* __restrict__ Wn,
    const char* __restrict__ Wh,
    const float* __restrict__ hidden,
    const float* __restrict__ b_ir, const float* __restrict__ b_iz,
    const float* __restrict__ b_in, const float* __restrict__ b_hr,
    const float* __restrict__ b_hz, const float* __restrict__ b_hn,
    float* __restrict__ out)
{
    __shared__ __attribute__((aligned(128))) char smem[4 * TBYTES];

    const int tid  = threadIdx.x;
    const int lane = tid & 63;
    const int wid  = tid >> 6;
    const int wm   = wid >> 2;     // 0..1 : M-half (128 rows)
    const int wn   = wid & 3;      // 0..3 : 16-col slice (nfr = wn)

    // linear, b-fastest: consecutive blocks share the weight panel; A L3-hot.
    const int nb   = (int)blockIdx.x;
    const int bblk = nb & 31;       // 32 b-blocks
    const int hblk = nb >> 5;       // 64 h-blocks
    const int b0 = bblk * BM;
    const int h0 = hblk * GBN;

    // staging roles: waves 0..3 stage A frags mfr=4w..4w+3; waves 4..7 stage
    // gate (wid-4)'s full 4KB tile. Both are 4KB contiguous in ws.
    const int gg = (wid >= 4) ? (wid - 4) : 0;
    const char* gW = (gg == 0) ? Wr : (gg == 1) ? Wz : (gg == 2) ? Wn : Wh;
    const char* psrc = (wid < 4)
        ? Abf + (size_t)bblk * 2097152 + (size_t)(4 * wid) * 1024 + (lane << 4)
        : gW + (size_t)hblk * 524288 + (lane << 4);
    const size_t pstep = (wid < 4) ? 16384 : 4096;   // ws bytes per K-tile
    const int dst = (wid < 4) ? (4 * wid) * 1024 : (16384 + gg * 4096);

    f32x4 acc[4][8];
#pragma unroll
    for (int g = 0; g < 4; ++g)
#pragma unroll
        for (int m = 0; m < 8; ++m) acc[g][m] = (f32x4)0.0f;

#define STAGE(x) do {                                                          \
        const char* s_ = psrc + (size_t)(x) * pstep;                           \
        char* l_ = smem + ((x) & 3) * TBYTES + dst;                            \
        gld16(s_, l_); gld16(s_ + 1024, l_ + 1024);                            \
        gld16(s_ + 2048, l_ + 2048); gld16(s_ + 3072, l_ + 3072);              \
    } while (0)

#define RD(dA_, dF_, x) do {                                                   \
        const char* cb_ = smem + ((x) & 3) * TBYTES;                           \
        _Pragma("unroll")                                                      \
        for (int mf = 0; mf < 8; ++mf)                                         \
            dA_[mf] = *(const bf16x8*)(cb_ + (wm * 8 + mf) * 1024 + (lane << 4)); \
        _Pragma("unroll")                                                      \
        for (int g = 0; g < 4; ++g)                                            \
            dF_[g] = *(const bf16x8*)(cb_ + 16384 + g * 4096 + wn * 1024 + (lane << 4)); \
    } while (0)

#define MM(acc_, a_, b_) acc_ = __builtin_amdgcn_mfma_f32_16x16x32_bf16(a_, b_, acc_, 0, 0, 0)

#define MFMA32(A_, F_) do {                                                    \
        __builtin_amdgcn_s_setprio(1);                                         \
        _Pragma("unroll")                                                      \
        for (int g = 0; g < 4; ++g)                                            \
            _Pragma("unroll")                                                  \
            for (int mf = 0; mf < 8; ++mf)                                     \
                MM(acc[g][mf], A_[mf], F_[g]);                                 \
        __builtin_amdgcn_s_setprio(0);                                         \
    } while (0)

#define SB0 __builtin_amdgcn_sched_barrier(0)

#define BODY(t, cA, cF, nA, nF) do {                                           \
        asm volatile("s_waitcnt lgkmcnt(0)" ::: "memory");                     \
        SB0;                                                                   \
        if ((t) + 3 < NT) STAGE((t) + 3);                                      \
        if ((t) + 1 < NT) RD(nA, nF, (t) + 1);                                 \
        MFMA32(cA, cF);                                                        \
        if ((t) <= NT - 4) { asm volatile("s_waitcnt vmcnt(4)" ::: "memory"); }\
        else               { asm volatile("s_waitcnt vmcnt(0)" ::: "memory"); }\
        SB0;                                                                   \
        __builtin_amdgcn_s_barrier();                                          \
    } while (0)

    bf16x8 a0[8], f0[4], a1[8], f1[4];

    // ---- prologue: stage tiles 0..2; publish bufs 0,1; preload reads(0) ----
    STAGE(0); STAGE(1); STAGE(2);
    asm volatile("s_waitcnt vmcnt(4)" ::: "memory");   // bufs 0,1 complete
    SB0;
    __builtin_amdgcn_s_barrier();
    RD(a0, f0, 0);

#pragma unroll 1
    for (int t = 0; t < NT; t += 2) {
        BODY(t,     a0, f0, a1, f1);
        BODY(t + 1, a1, f1, a0, f0);
    }

    // ---- epilogue: biases + gate math + combine, fp32 out ----
    const int r4 = (lane >> 4) * 4;
    const int cn = lane & 15;
    {
        const int h = h0 + wn * 16 + cn;
        const float br = b_ir[h] + b_hr[h];
        const float bz = b_iz[h] + b_hz[h];
        const float bn = b_in[h];
        const float bh = b_hn[h];
#pragma unroll
        for (int m = 0; m < 8; ++m) {
            const int brow = b0 + wm * 128 + m * 16 + r4;
#pragma unroll
            for (int j = 0; j < 4; ++j) {
                const size_t idx = (size_t)(brow + j) * H_DIM + h;
                const float r = sigmoidf_(acc[0][m][j] + br);
                const float z = sigmoidf_(acc[1][m][j] + bz);
                const float n = sigmoidf_(acc[2][m][j] + bn + r * (acc[3][m][j] + bh));
                out[idx] = (1.0f - z) * hidden[idx] + z * n;
            }
        }
    }
#undef STAGE
#undef RD
#undef MM
#undef MFMA32
#undef SB0
#undef BODY
}

// ---------------- fallback: round-1 fp32-staged kernel (known passing) ----------------
__global__ __launch_bounds__(THREADS, 2) void gru_fused_f32(
    const float* __restrict__ input, const float* __restrict__ hidden,
    const float* __restrict__ w_ir, const float* __restrict__ b_ir,
    const float* __restrict__ w_iz, const float* __restrict__ b_iz,
    const float* __restrict__ w_in, const float* __restrict__ b_in,
    const float* __restrict__ w_hr, const float* __restrict__ b_hr,
    const float* __restrict__ w_hz, const float* __restrict__ b_hz,
    const float* __restrict__ w_hn, const float* __restrict__ b_hn,
    float* __restrict__ out)
{
    __shared__ int smem[2 * 10240];
    const int tid  = threadIdx.x;
    const int lane = tid & 63;
    const int wid  = tid >> 6;
    const int wm   = wid >> 2;
    const int wn   = wid & 3;
    const int bblk = blockIdx.x & 63;
    const int hblk = blockIdx.x >> 6;
    const int b0 = bblk * 128;
    const int h0 = hblk * 128;
    const int srow = tid >> 2;
    const int sc   = tid & 3;
    const float4* gA  = (const float4*)(input + (size_t)(b0 + srow) * D_DIM + sc * 8);
    const size_t woff = (size_t)(h0 + srow) * D_DIM + sc * 8;
    const float4* gIr = (const float4*)(w_ir + woff);
    const float4* gHr = (const float4*)(w_hr + woff);
    const float4* gIz = (const float4*)(w_iz + woff);
    const float4* gHz = (const float4*)(w_hz + woff);
    const float4* gIn = (const float4*)(w_in + woff);
    const float4* gHn = (const float4*)(w_hn + woff);
    const int wr_ints = (srow >> 4) * 256 + ((sc * 16 + (srow & 15)) * 4);

    f32x4 accR[4][2], accZ[4][2], accN[4][2], accH[4][2];
#pragma unroll
    for (int mf = 0; mf < 4; ++mf)
#pragma unroll
        for (int nf = 0; nf < 2; ++nf) {
            accR[mf][nf] = (f32x4)0.0f; accZ[mf][nf] = (f32x4)0.0f;
            accN[mf][nf] = (f32x4)0.0f; accH[mf][nf] = (f32x4)0.0f;
        }
    float4 La0, La1, Lr0, Lr1, Lr2, Lr3, Lz0, Lz1, Lz2, Lz3, Ln0, Ln1, Lh0, Lh1;
#define LOADREGS(s) do { const int o = (s) * 8;                          \
        La0 = gA[o];  La1 = gA[o + 1];                                   \
        Lr0 = gIr[o]; Lr1 = gIr[o + 1]; Lr2 = gHr[o]; Lr3 = gHr[o + 1];  \
        Lz0 = gIz[o]; Lz1 = gIz[o + 1]; Lz2 = gHz[o]; Lz3 = gHz[o + 1];  \
        Ln0 = gIn[o]; Ln1 = gIn[o + 1];                                  \
        Lh0 = gHn[o]; Lh1 = gHn[o + 1]; } while (0)
#define WRITELDS(pp) do { const int wb = (pp) * 10240 + wr_ints;          \
        *(i32x4*)&smem[wb]        = pack8(La0, La1);                      \
        *(i32x4*)&smem[wb + 2048] = pack8(Lr0 + Lr2, Lr1 + Lr3);          \
        *(i32x4*)&smem[wb + 4096] = pack8(Lz0 + Lz2, Lz1 + Lz3);          \
        *(i32x4*)&smem[wb + 6144] = pack8(Ln0, Ln1);                      \
        *(i32x4*)&smem[wb + 8192] = pack8(Lh0, Lh1); } while (0)
#define COMPUTE(pp) do {                                                  \
        const int cb = (pp) * 10240;                                      \
        const bf16x8* Af = (const bf16x8*)&smem[cb];                      \
        const bf16x8* Br = (const bf16x8*)&smem[cb + 2048];               \
        const bf16x8* Bz = (const bf16x8*)&smem[cb + 4096];               \
        const bf16x8* Bn = (const bf16x8*)&smem[cb + 6144];               \
        const bf16x8* Bh = (const bf16x8*)&smem[cb + 8192];               \
        bf16x8 afr[4];                                                    \
        _Pragma("unroll")                                                 \
        for (int mf = 0; mf < 4; ++mf)                                    \
            afr[mf] = Af[(wm * 4 + mf) * 64 + lane];                      \
        _Pragma("unroll")                                                 \
        for (int nf = 0; nf < 2; ++nf) {                                  \
            const int bi = (wn * 2 + nf) * 64 + lane;                     \
            bf16x8 fr = Br[bi], fz = Bz[bi], fn = Bn[bi], fh = Bh[bi];    \
            _Pragma("unroll")                                             \
            for (int mf = 0; mf < 4; ++mf) {                              \
                accR[mf][nf] = __builtin_amdgcn_mfma_f32_16x16x32_bf16(afr[mf], fr, accR[mf][nf], 0, 0, 0); \
                accZ[mf][nf] = __builtin_amdgcn_mfma_f32_16x16x32_bf16(afr[mf], fz, accZ[mf][nf], 0, 0, 0); \
                accN[mf][nf] = __builtin_amdgcn_mfma_f32_16x16x32_bf16(afr[mf], fn, accN[mf][nf], 0, 0, 0); \
                accH[mf][nf] = __builtin_amdgcn_mfma_f32_16x16x32_bf16(afr[mf], fh, accH[mf][nf], 0, 0, 0); \
            }                                                             \
        } } while (0)
    LOADREGS(0);
    WRITELDS(0);
    __syncthreads();
#pragma unroll 1
    for (int s = 0; s < 128; ++s) {
        if (s + 1 < 128) LOADREGS(s + 1);
        COMPUTE(s & 1);
        if (s + 1 < 128) { WRITELDS((s + 1) & 1); __syncthreads(); }
    }
    const int r4 = (lane >> 4) * 4;
    const int cn = lane & 15;
#pragma unroll
    for (int nf = 0; nf < 2; ++nf) {
        const int h = h0 + wn * 32 + nf * 16 + cn;
        const float br = b_ir[h] + b_hr[h];
        const float bz = b_iz[h] + b_hz[h];
        const float bn = b_in[h];
        const float bh = b_hn[h];
#pragma unroll
        for (int mf = 0; mf < 4; ++mf) {
            const int brow = b0 + wm * 64 + mf * 16 + r4;
#pragma unroll
            for (int j = 0; j < 4; ++j) {
                const size_t idx = (size_t)(brow + j) * H_DIM + h;
                const float r = sigmoidf_(accR[mf][nf][j] + br);
                const float z = sigmoidf_(accZ[mf][nf][j] + bz);
                const float n = sigmoidf_(accN[mf][nf][j] + bn + r * (accH[mf][nf][j] + bh));
                out[idx] = (1.0f - z) * hidden[idx] + z * n;
            }
        }
    }
#undef LOADREGS
#undef WRITELDS
#undef COMPUTE
}

extern "C" void kernel_launch(void* const* d_in, const int* in_sizes, int n_in,
                              void* d_out, int out_size, void* d_ws, size_t ws_size,
                              hipStream_t stream) {
    const float* input  = (const float*)d_in[0];
    const float* hidden = (const float*)d_in[1];
    const float* w_ir = (const float*)d_in[2];  const float* b_ir = (const float*)d_in[3];
    const float* w_iz = (const float*)d_in[4];  const float* b_iz = (const float*)d_in[5];
    const float* w_in = (const float*)d_in[6];  const float* b_in = (const float*)d_in[7];
    const float* w_hr = (const float*)d_in[8];  const float* b_hr = (const float*)d_in[9];
    const float* w_hz = (const float*)d_in[10]; const float* b_hz = (const float*)d_in[11];
    const float* w_hn = (const float*)d_in[12]; const float* b_hn = (const float*)d_in[13];
    float* out = (float*)d_out;

    if (ws_size >= WS_NEED) {
        char* ws = (char*)d_ws;
        prep_w_t<<<dim3(8192, 4), dim3(256), 0, stream>>>(
            w_ir, w_hr, w_iz, w_hz, w_in, w_hn, ws);
        prep_a_t<<<dim3(16384), dim3(256), 0, stream>>>(input, ws + WS_A);
        gru_bf16<<<dim3((B_DIM / BM) * (H_DIM / GBN)), dim3(THREADS), 0, stream>>>(
            ws + WS_A, ws + WS_WR, ws + WS_WZ, ws + WS_WN, ws + WS_WH,
            hidden, b_ir, b_iz, b_in, b_hr, b_hz, b_hn, out);
    } else {
        gru_fused_f32<<<dim3(2048), dim3(THREADS), 0, stream>>>(
            input, hidden, w_ir, b_ir, w_iz, b_iz, w_in, b_in,
            w_hr, b_hr, w_hz, b_hz, w_hn, b_hn, out);
    }
}